// Round 5
// baseline (534.907 us; speedup 1.0000x reference)
//
#include <hip/hip_runtime.h>
#include <math.h>

// Problem constants
#define Bc    64
#define Cc    512
#define Fc    48
#define NTOT  32768
#define TT    49
#define NS    5            // sequences per 256-thread block
#define NBLK  ((NTOT + NS - 1) / NS)   // 6554 virtual blocks
#define GRID  1792         // 7 persistent blocks per CU (224 per XCD)
// attn scale 0.5 * log2(e) folded into q-columns of qkv_w at pack time
#define QSCALE 0.72134752044448169f
// gelu(g) ~= g / (1 + exp2(C1*g + C2*g^3))  (validated R2-R4)
#define GC1 (-2.3022082f)
#define GC2 (-0.10294324f)

#define EXP2(x) __builtin_amdgcn_exp2f(x)
#define RCP(x)  __builtin_amdgcn_rcpf(x)

using h2 = decltype(__builtin_amdgcn_cvt_pkrtz(0.f, 0.f));   // v2f16

__device__ __forceinline__ h2 PK(float a, float b) {         // round-toward-zero pack
    return __builtin_amdgcn_cvt_pkrtz(a, b);
}
__device__ __forceinline__ unsigned H2U(h2 h) { return __builtin_bit_cast(unsigned, h); }
__device__ __forceinline__ h2 U2H(unsigned u) { return __builtin_bit_cast(h2, u); }

__device__ __forceinline__ float DOT2(h2 a, h2 b, float c) {
#if __has_builtin(__builtin_amdgcn_fdot2)
    return __builtin_amdgcn_fdot2(a, b, c, false);   // fp32 accumulate
#else
    return fmaf((float)a[0], (float)b[0], fmaf((float)a[1], (float)b[1], c));
#endif
}
__device__ __forceinline__ unsigned pack_rte(float a, float b) {  // accurate pack (setup)
    h2 h; h[0] = (_Float16)a; h[1] = (_Float16)b;
    return __builtin_bit_cast(unsigned, h);
}

// ---- ws dword offsets ----
#define OFF_QKVW 0        // [l][j<48][dp<8] h2 pairs over d; LN1-s + qscale folded (768)
#define OFF_QKVB 768      // [l][48] f32, LN1-b folded, q pre-scaled                 (96)
#define OFF_OUTW 864      // [l][d<16][dp<8] pairs over dd                           (256)
#define OFF_OUTB 1120     // [l][16] f32                                             (32)
#define OFF_FF1W 1152     // [l][j<64][dp<8] pairs over d; LN2-s folded             (1024)
#define OFF_FF1B 2176     // [l][64] f32, LN2-b folded                               (128)
#define OFF_FF2W 2304     // [l][jp<32][d<16] pairs over j                          (1024)
#define OFF_FF2B 3328     // [l][16] f32                                             (32)
#define OFF_C2HW 3360     // [o<256][dp<8] pairs over d                             (2048)
#define OFF_C2HB 5408     // [256] f32                                               (256)
#define OFF_FBTE 5664     // [f<48][d<16] f32 = fb + te[role]                        (768)
#define WS_DWORDS 6432

__global__ __launch_bounds__(256)
void pack_kernel(const float* __restrict__ qkv_w, const float* __restrict__ qkv_b,
                 const float* __restrict__ out_w, const float* __restrict__ out_b,
                 const float* __restrict__ ff1_w, const float* __restrict__ ff1_b,
                 const float* __restrict__ ff2_w, const float* __restrict__ ff2_b,
                 const float* __restrict__ c2h_w, const float* __restrict__ c2h_b,
                 const float* __restrict__ fb,    const float* __restrict__ te,
                 const int*   __restrict__ role,
                 const float* __restrict__ ln1_s, const float* __restrict__ ln1_b,
                 const float* __restrict__ ln2_s, const float* __restrict__ ln2_b,
                 unsigned* __restrict__ ws)
{
    const int t = threadIdx.x;
    float* wsf = (float*)ws;
    for (int i = t; i < 768; i += 256) {          // qkvW pairs over d, LN1-s folded
        int dp = i & 7, jl = i >> 3, j = jl % 48, l = jl / 48;
        float w0 = qkv_w[(l*16 + 2*dp    )*48 + j] * ln1_s[l*16 + 2*dp];
        float w1 = qkv_w[(l*16 + 2*dp + 1)*48 + j] * ln1_s[l*16 + 2*dp + 1];
        if (j < 16) { w0 *= QSCALE; w1 *= QSCALE; }
        ws[OFF_QKVW + i] = pack_rte(w0, w1);
    }
    for (int i = t; i < 96; i += 256) {           // qkvB + ln1_b @ W, q pre-scaled
        int j = i % 48, l = i / 48;
        float a = qkv_b[i];
        for (int d = 0; d < 16; ++d) a += ln1_b[l*16+d] * qkv_w[(l*16+d)*48 + j];
        wsf[OFF_QKVB + i] = a * (j < 16 ? QSCALE : 1.0f);
    }
    for (int i = t; i < 256; i += 256) {          // outW pairs over dd
        int dp = i & 7, dl = i >> 3, d = dl % 16, l = dl / 16;
        ws[OFF_OUTW + i] = pack_rte(out_w[l*256 + (2*dp)*16 + d],
                                    out_w[l*256 + (2*dp+1)*16 + d]);
    }
    for (int i = t; i < 32; i += 256) wsf[OFF_OUTB + i] = out_b[i];
    for (int i = t; i < 1024; i += 256) {         // ff1W pairs over d, LN2-s folded
        int dp = i & 7, jl = i >> 3, j = jl % 64, l = jl / 64;
        ws[OFF_FF1W + i] = pack_rte(ff1_w[l*1024 + (2*dp)*64 + j] * ln2_s[l*16 + 2*dp],
                                    ff1_w[l*1024 + (2*dp+1)*64 + j] * ln2_s[l*16 + 2*dp+1]);
    }
    for (int i = t; i < 128; i += 256) {          // ff1B + ln2_b @ W
        int j = i % 64, l = i / 64;
        float a = ff1_b[i];
        for (int d = 0; d < 16; ++d) a += ln2_b[l*16+d] * ff1_w[(l*16+d)*64 + j];
        wsf[OFF_FF1B + i] = a;
    }
    for (int i = t; i < 1024; i += 256) {         // ff2W pairs over j
        int d = i & 15, jpl = i >> 4, jp = jpl % 32, l = jpl / 32;
        ws[OFF_FF2W + i] = pack_rte(ff2_w[l*1024 + (2*jp)*16 + d],
                                    ff2_w[l*1024 + (2*jp+1)*16 + d]);
    }
    for (int i = t; i < 32; i += 256) wsf[OFF_FF2B + i] = ff2_b[i];
    for (int i = t; i < 2048; i += 256) {         // c2hW pairs over d
        int dp = i & 7, o = i >> 3;
        ws[OFF_C2HW + i] = pack_rte(c2h_w[(2*dp)*256 + o], c2h_w[(2*dp+1)*256 + o]);
    }
    for (int i = t; i < 256; i += 256) wsf[OFF_C2HB + i] = c2h_b[i];
    for (int i = t; i < 768; i += 256) {          // fbte = fb + te[role]
        int d = i & 15, f = i >> 4;
        wsf[OFF_FBTE + i] = fb[f*16 + d] + te[role[f]*16 + d];
    }
}

// Per-seq LDS: K rows as f16 dim-pairs (stride 3 uint4 = 48B, b128-aligned);
// V as f16 KEY-pair dwords: Vp[pair][d] = (v[2p][d], v[2p+1][d]) -> PV is dot2
// over keys with fp32 accumulation. Pad key 49: Kp row zero -> p = 1 -> lsum -= 1,
// V high half zero.
struct __align__(16) SeqSh {
    uint4 Kp[50][3];
    uint4 Vp[25][5];
    unsigned clsP[8];
};

__global__ __launch_bounds__(256, 7)
void enc_kernel(const float* __restrict__ cf,  const float* __restrict__ fe,
                const float* __restrict__ cls_tok,
                const unsigned* __restrict__ wsp, float* __restrict__ out)
{
    const unsigned ut = threadIdx.x;
    const int seq = ut / 49u;
    const int row = ut - seq * 49u;

    __shared__ SeqSh S[NS];
    const float* wsf = (const float*)wsp;
    const h2 ONE = PK(1.f, 1.f);

    // Persistent blocks: 7/CU resident, grid-stride over virtual blocks.
    for (int vb = blockIdx.x; vb < NBLK; vb += GRID) {
        const int n0  = vb * NS;
        const int n   = n0 + seq;
        const bool act = (seq < NS) && (n < NTOT);
        const int b = n >> 9, c = n & 511;

        // ---- embedding ----
        float x[16];
        if (act) {
            if (row == 0) {
                #pragma unroll
                for (int d = 0; d < 16; ++d) x[d] = cls_tok[d];
            } else {
                const int f = row - 1;
                const float s = cf[((long)b * Fc + f) * Cc + c];
                const float4* fep = (const float4*)(fe + f*16);
                const float4* fbp = (const float4*)(wsf + OFF_FBTE + f*16);
                #pragma unroll
                for (int j = 0; j < 4; ++j) {
                    float4 e = fep[j], t4 = fbp[j];
                    x[4*j+0] = fmaf(s, e.x, t4.x); x[4*j+1] = fmaf(s, e.y, t4.y);
                    x[4*j+2] = fmaf(s, e.z, t4.z); x[4*j+3] = fmaf(s, e.w, t4.w);
                }
            }
        } else {
            #pragma unroll
            for (int d = 0; d < 16; ++d) x[d] = 0.f;
        }

        for (int l = 0; l < 2; ++l) {
            h2 hp[8], qp[8];
            // ---- LN1 (scale/bias folded into weights): xhat = x*rr - mu*rr ----
            if (act) {
                float mu = 0.f;
                #pragma unroll
                for (int d = 0; d < 16; ++d) mu += x[d];
                mu *= 0.0625f;
                float var = 0.f;
                #pragma unroll
                for (int d = 0; d < 16; ++d) { float dv = x[d]-mu; var = fmaf(dv,dv,var); }
                const float rr = rsqrtf(var*0.0625f + 1e-5f);
                const float nb = -mu * rr;
                #pragma unroll
                for (int p = 0; p < 8; ++p)
                    hp[p] = PK(fmaf(x[2*p], rr, nb), fmaf(x[2*p+1], rr, nb));

                // ---- QKV via dot2 (weights uniform -> scalar loads) ----
                const unsigned* W = wsp + OFF_QKVW + l*384;
                const float* Bb = wsf + OFF_QKVB + l*48;
                #pragma unroll
                for (int j = 0; j < 16; j += 2) {      // q (pre-scaled)
                    float a0 = Bb[j], a1 = Bb[j+1];
                    #pragma unroll
                    for (int dp = 0; dp < 8; ++dp) {
                        a0 = DOT2(hp[dp], U2H(W[ j   *8+dp]), a0);
                        a1 = DOT2(hp[dp], U2H(W[(j+1)*8+dp]), a1);
                    }
                    qp[j>>1] = PK(a0, a1);
                }
                unsigned kdw[8];
                #pragma unroll
                for (int j = 0; j < 16; j += 2) {      // k
                    float a0 = Bb[16+j], a1 = Bb[17+j];
                    #pragma unroll
                    for (int dp = 0; dp < 8; ++dp) {
                        a0 = DOT2(hp[dp], U2H(W[(16+j)*8+dp]), a0);
                        a1 = DOT2(hp[dp], U2H(W[(17+j)*8+dp]), a1);
                    }
                    kdw[j>>1] = H2U(PK(a0, a1));
                }
                float vf[16];
                #pragma unroll
                for (int j = 0; j < 16; ++j) {         // v
                    float a = Bb[32+j];
                    #pragma unroll
                    for (int dp = 0; dp < 8; ++dp)
                        a = DOT2(hp[dp], U2H(W[(32+j)*8+dp]), a);
                    vf[j] = a;
                }
                S[seq].Kp[row][0] = make_uint4(kdw[0],kdw[1],kdw[2],kdw[3]);
                S[seq].Kp[row][1] = make_uint4(kdw[4],kdw[5],kdw[6],kdw[7]);
                if (row < 48) {
                    _Float16* vh = (_Float16*)&S[seq].Vp[row>>1][0];
                    const int pr = row & 1;
                    #pragma unroll
                    for (int d = 0; d < 16; ++d) vh[2*d + pr] = (_Float16)vf[d];
                } else {   // row 48 owns pair 24 fully; key 49 half = 0
                    unsigned* vw = (unsigned*)&S[seq].Vp[24][0];
                    #pragma unroll
                    for (int d = 0; d < 16; ++d) vw[d] = H2U(PK(vf[d], 0.f));
                }
                if (row == 0) {
                    const uint4 z = make_uint4(0,0,0,0);
                    S[seq].Kp[49][0] = z; S[seq].Kp[49][1] = z;
                }
            }
            __syncthreads();   // K/V tile ready

            if (act) {
                // ---- attention: key-pair loop, no-max softmax in exp2 domain ----
                float ctx[16];
                #pragma unroll
                for (int d = 0; d < 16; ++d) ctx[d] = 0.f;
                float ls0=0.f, ls1=0.f, ls2=0.f, ls3=0.f;
                #pragma unroll 5
                for (int kp = 0; kp < 25; ++kp) {
                    const uint4 ka0 = S[seq].Kp[2*kp  ][0], ka1 = S[seq].Kp[2*kp  ][1];
                    const uint4 kb0 = S[seq].Kp[2*kp+1][0], kb1 = S[seq].Kp[2*kp+1][1];
                    float sa0 = DOT2(qp[0],U2H(ka0.x), DOT2(qp[1],U2H(ka0.y), 0.f));
                    float sb0 = DOT2(qp[0],U2H(kb0.x), DOT2(qp[1],U2H(kb0.y), 0.f));
                    float sa1 = DOT2(qp[2],U2H(ka0.z), DOT2(qp[3],U2H(ka0.w), 0.f));
                    float sb1 = DOT2(qp[2],U2H(kb0.z), DOT2(qp[3],U2H(kb0.w), 0.f));
                    float sa2 = DOT2(qp[4],U2H(ka1.x), DOT2(qp[5],U2H(ka1.y), 0.f));
                    float sb2 = DOT2(qp[4],U2H(kb1.x), DOT2(qp[5],U2H(kb1.y), 0.f));
                    float sa3 = DOT2(qp[6],U2H(ka1.z), DOT2(qp[7],U2H(ka1.w), 0.f));
                    float sb3 = DOT2(qp[6],U2H(kb1.z), DOT2(qp[7],U2H(kb1.w), 0.f));
                    const h2 pp0 = PK(EXP2(sa0), EXP2(sb0));
                    const h2 pp1 = PK(EXP2(sa1), EXP2(sb1));
                    const h2 pp2 = PK(EXP2(sa2), EXP2(sb2));
                    const h2 pp3 = PK(EXP2(sa3), EXP2(sb3));
                    ls0 = DOT2(pp0, ONE, ls0); ls1 = DOT2(pp1, ONE, ls1);
                    ls2 = DOT2(pp2, ONE, ls2); ls3 = DOT2(pp3, ONE, ls3);
                    const uint4 v0 = S[seq].Vp[kp][0], v1 = S[seq].Vp[kp][1];
                    const uint4 v2 = S[seq].Vp[kp][2], v3 = S[seq].Vp[kp][3];
                    ctx[ 0]=DOT2(pp0,U2H(v0.x),ctx[ 0]); ctx[ 1]=DOT2(pp0,U2H(v0.y),ctx[ 1]);
                    ctx[ 2]=DOT2(pp0,U2H(v0.z),ctx[ 2]); ctx[ 3]=DOT2(pp0,U2H(v0.w),ctx[ 3]);
                    ctx[ 4]=DOT2(pp1,U2H(v1.x),ctx[ 4]); ctx[ 5]=DOT2(pp1,U2H(v1.y),ctx[ 5]);
                    ctx[ 6]=DOT2(pp1,U2H(v1.z),ctx[ 6]); ctx[ 7]=DOT2(pp1,U2H(v1.w),ctx[ 7]);
                    ctx[ 8]=DOT2(pp2,U2H(v2.x),ctx[ 8]); ctx[ 9]=DOT2(pp2,U2H(v2.y),ctx[ 9]);
                    ctx[10]=DOT2(pp2,U2H(v2.z),ctx[10]); ctx[11]=DOT2(pp2,U2H(v2.w),ctx[11]);
                    ctx[12]=DOT2(pp3,U2H(v3.x),ctx[12]); ctx[13]=DOT2(pp3,U2H(v3.y),ctx[13]);
                    ctx[14]=DOT2(pp3,U2H(v3.z),ctx[14]); ctx[15]=DOT2(pp3,U2H(v3.w),ctx[15]);
                }
                // pad key 49 contributed exp2(0)=1 per head
                ls0 -= 1.f; ls1 -= 1.f; ls2 -= 1.f; ls3 -= 1.f;
                const float i0 = RCP(ls0), i1 = RCP(ls1), i2 = RCP(ls2), i3 = RCP(ls3);
                #pragma unroll
                for (int d = 0; d < 4;  ++d) ctx[d] *= i0;
                #pragma unroll
                for (int d = 4; d < 8;  ++d) ctx[d] *= i1;
                #pragma unroll
                for (int d = 8; d < 12; ++d) ctx[d] *= i2;
                #pragma unroll
                for (int d = 12; d < 16; ++d) ctx[d] *= i3;

                // ---- out-proj + residual ----
                h2 cp[8];
                #pragma unroll
                for (int p = 0; p < 8; ++p) cp[p] = PK(ctx[2*p], ctx[2*p+1]);
                const unsigned* OW = wsp + OFF_OUTW + l*128;
                const float* OB = wsf + OFF_OUTB + l*16;
                #pragma unroll
                for (int d = 0; d < 16; ++d) {
                    float a = OB[d];
                    #pragma unroll
                    for (int dp = 0; dp < 8; ++dp) a = DOT2(cp[dp], U2H(OW[d*8+dp]), a);
                    x[d] += a;
                }

                // ---- LN2 (folded) ----
                float mu = 0.f;
                #pragma unroll
                for (int d = 0; d < 16; ++d) mu += x[d];
                mu *= 0.0625f;
                float var = 0.f;
                #pragma unroll
                for (int d = 0; d < 16; ++d) { float dv = x[d]-mu; var = fmaf(dv,dv,var); }
                const float rr = rsqrtf(var*0.0625f + 1e-5f);
                const float nb = -mu * rr;
                #pragma unroll
                for (int p = 0; p < 8; ++p)
                    hp[p] = PK(fmaf(x[2*p], rr, nb), fmaf(x[2*p+1], rr, nb));

                // ---- FF: 16->64->gelu->16, j-pair fused, all dot2 ----
                const unsigned* F1 = wsp + OFF_FF1W + l*512;
                const float*    B1 = wsf + OFF_FF1B + l*64;
                const unsigned* F2 = wsp + OFF_FF2W + l*512;
                float acc2[16];
                #pragma unroll
                for (int d = 0; d < 16; ++d) acc2[d] = wsf[OFF_FF2B + l*16 + d];
                #pragma unroll 4
                for (int jp = 0; jp < 32; ++jp) {
                    float g0 = B1[2*jp], g1 = B1[2*jp+1];
                    #pragma unroll
                    for (int dp = 0; dp < 8; ++dp) {
                        g0 = DOT2(hp[dp], U2H(F1[(2*jp  )*8+dp]), g0);
                        g1 = DOT2(hp[dp], U2H(F1[(2*jp+1)*8+dp]), g1);
                    }
                    const float u0 = g0 * fmaf(GC2, g0*g0, GC1);
                    const float e0 = g0 * RCP(1.0f + EXP2(u0));
                    const float u1 = g1 * fmaf(GC2, g1*g1, GC1);
                    const float e1 = g1 * RCP(1.0f + EXP2(u1));
                    const h2 gp = PK(e0, e1);
                    #pragma unroll
                    for (int d = 0; d < 16; ++d)
                        acc2[d] = DOT2(gp, U2H(F2[jp*16+d]), acc2[d]);
                }
                #pragma unroll
                for (int d = 0; d < 16; ++d) x[d] += acc2[d];
            }
            __syncthreads();   // attn readers done before next layer overwrites LDS
        }

        // ---- head: cls row packed to LDS, lane ut owns output col o = ut ----
        if (act && row == 0) {
            #pragma unroll
            for (int p = 0; p < 8; ++p) S[seq].clsP[p] = H2U(PK(x[2*p], x[2*p+1]));
        }
        __syncthreads();

        const uint4* cw = (const uint4*)(wsp + OFF_C2HW + ut*8);
        const uint4 w0 = cw[0], w1 = cw[1];
        const float bt = wsf[OFF_C2HB + ut];
        #pragma unroll
        for (int oo = 0; oo < NS; ++oo) {
            const int n2 = n0 + oo;
            if (n2 < NTOT) {
                float a = bt;
                a = DOT2(U2H(S[oo].clsP[0]), U2H(w0.x), a);
                a = DOT2(U2H(S[oo].clsP[1]), U2H(w0.y), a);
                a = DOT2(U2H(S[oo].clsP[2]), U2H(w0.z), a);
                a = DOT2(U2H(S[oo].clsP[3]), U2H(w0.w), a);
                a = DOT2(U2H(S[oo].clsP[4]), U2H(w1.x), a);
                a = DOT2(U2H(S[oo].clsP[5]), U2H(w1.y), a);
                a = DOT2(U2H(S[oo].clsP[6]), U2H(w1.z), a);
                a = DOT2(U2H(S[oo].clsP[7]), U2H(w1.w), a);
                out[((long)(n2 >> 9) * 256 + ut) * 512 + (n2 & 511)] = a;
            }
        }
        // No barrier needed here: next iteration's first LDS writes (Kp/Vp) are
        // disjoint from clsP, and all Kp/Vp reuse is fenced by the layer barriers.
    }
}

extern "C" void kernel_launch(void* const* d_in, const int* in_sizes, int n_in,
                              void* d_out, int out_size, void* d_ws, size_t ws_size,
                              hipStream_t stream) {
    const float* cf       = (const float*)d_in[0];
    const float* fe       = (const float*)d_in[1];
    const float* fb       = (const float*)d_in[2];
    const float* cls_tok  = (const float*)d_in[3];
    const float* te       = (const float*)d_in[4];
    const int*   role_ids = (const int*)  d_in[5];
    const float* ln1_s    = (const float*)d_in[6];
    const float* ln1_b    = (const float*)d_in[7];
    const float* qkv_w    = (const float*)d_in[8];
    const float* qkv_b    = (const float*)d_in[9];
    const float* out_w    = (const float*)d_in[10];
    const float* out_b    = (const float*)d_in[11];
    const float* ln2_s    = (const float*)d_in[12];
    const float* ln2_b    = (const float*)d_in[13];
    const float* ff1_w    = (const float*)d_in[14];
    const float* ff1_b    = (const float*)d_in[15];
    const float* ff2_w    = (const float*)d_in[16];
    const float* ff2_b    = (const float*)d_in[17];
    const float* c2h_w    = (const float*)d_in[18];
    const float* c2h_b    = (const float*)d_in[19];
    float* out = (float*)d_out;
    unsigned* ws = (unsigned*)d_ws;

    pack_kernel<<<1, 256, 0, stream>>>(qkv_w, qkv_b, out_w, out_b, ff1_w, ff1_b,
                                       ff2_w, ff2_b, c2h_w, c2h_b, fb, te,
                                       role_ids, ln1_s, ln1_b, ln2_s, ln2_b, ws);
    enc_kernel<<<GRID, 256, 0, stream>>>(cf, fe, cls_tok, ws, out);
}

// Round 6
// 417.677 us; speedup vs baseline: 1.2807x; 1.2807x over previous
//
#include <hip/hip_runtime.h>
#include <math.h>

// Problem constants
#define Bc    64
#define Cc    512
#define Fc    48
#define NTOT  32768
#define TT    49
#define NS    5            // sequences per 256-thread block
#define NBLK  ((NTOT + NS - 1) / NS)   // 6554 blocks
// attn scale 0.5 * log2(e) folded into q-columns of qkv_w at pack time
#define QSCALE 0.72134752044448169f
// gelu(g) ~= g / (1 + exp2(C1*g + C2*g^3))  (validated R2-R5)
#define GC1 (-2.3022082f)
#define GC2 (-0.10294324f)

#define EXP2(x) __builtin_amdgcn_exp2f(x)
#define RCP(x)  __builtin_amdgcn_rcpf(x)

using h2 = decltype(__builtin_amdgcn_cvt_pkrtz(0.f, 0.f));   // v2f16
typedef _Float16 f16x8 __attribute__((ext_vector_type(8)));
typedef float    f32x4 __attribute__((ext_vector_type(4)));

#define MFMA16(a,b,c) __builtin_amdgcn_mfma_f32_16x16x32_f16((a),(b),(c),0,0,0)

__device__ __forceinline__ h2 PK(float a, float b) {         // round-toward-zero pack
    return __builtin_amdgcn_cvt_pkrtz(a, b);
}
__device__ __forceinline__ unsigned H2U(h2 h) { return __builtin_bit_cast(unsigned, h); }
__device__ __forceinline__ h2 U2H(unsigned u) { return __builtin_bit_cast(h2, u); }

__device__ __forceinline__ float DOT2(h2 a, h2 b, float c) {
#if __has_builtin(__builtin_amdgcn_fdot2)
    return __builtin_amdgcn_fdot2(a, b, c, false);   // fp32 accumulate
#else
    return fmaf((float)a[0], (float)b[0], fmaf((float)a[1], (float)b[1], c));
#endif
}
__device__ __forceinline__ unsigned pack_rte(float a, float b) {  // accurate pack (setup)
    h2 h; h[0] = (_Float16)a; h[1] = (_Float16)b;
    return __builtin_bit_cast(unsigned, h);
}
__device__ __forceinline__ float gelu1(float g) {
    const float u = g * fmaf(GC2, g * g, GC1);
    return g * RCP(1.0f + EXP2(u));
}

// ---- ws dword offsets ----
#define OFF_QKVW 0        // [l][j<48][dp<8] h2 pairs over d; LN1-s + qscale folded (768)
#define OFF_QKVB 768      // [l][48] f32, LN1-b folded, q pre-scaled                 (96)
#define OFF_OUTW 864      // [l][d<16][dp<8] pairs over dd                           (256)
#define OFF_OUTB 1120     // [l][16] f32                                             (32)
#define OFF_C2HW 1152     // [o<256][dp<8] pairs over d                             (2048)
#define OFF_C2HB 3200     // [256] f32                                               (256)
#define OFF_FBTE 3456     // [f<48][d<16] f32 = fb + te[role]                        (768)
// MFMA-FF operands (frag order, LN2-s folded into W1, LN2-b into b1):
#define OFF_F1A  4224     // [l][mt<4][lane<64][4dw] f16 pairs: W1^T A-frags       (2048)
#define OFF_F2A  6272     // [l][kf<2][lane<64][4dw] f16 pairs: W2^T A-frags       (1024)
#define OFF_B1V  7296     // [l][mt<4][lane<64][4]  f32: b1' as C-frags            (2048)
#define OFF_B2V  9344     // [l][lane<64][4]        f32: b2 as C-frags              (512)
#define WS_DWORDS 9856

__global__ __launch_bounds__(256)
void pack_kernel(const float* __restrict__ qkv_w, const float* __restrict__ qkv_b,
                 const float* __restrict__ out_w, const float* __restrict__ out_b,
                 const float* __restrict__ ff1_w, const float* __restrict__ ff1_b,
                 const float* __restrict__ ff2_w, const float* __restrict__ ff2_b,
                 const float* __restrict__ c2h_w, const float* __restrict__ c2h_b,
                 const float* __restrict__ fb,    const float* __restrict__ te,
                 const int*   __restrict__ role,
                 const float* __restrict__ ln1_s, const float* __restrict__ ln1_b,
                 const float* __restrict__ ln2_s, const float* __restrict__ ln2_b,
                 unsigned* __restrict__ ws)
{
    const int gid = blockIdx.x * 256 + threadIdx.x;
    const int gs  = gridDim.x * 256;
    float* wsf = (float*)ws;
    for (int i = gid; i < 768; i += gs) {         // qkvW pairs over d, LN1-s folded
        int dp = i & 7, jl = i >> 3, j = jl % 48, l = jl / 48;
        float w0 = qkv_w[(l*16 + 2*dp    )*48 + j] * ln1_s[l*16 + 2*dp];
        float w1 = qkv_w[(l*16 + 2*dp + 1)*48 + j] * ln1_s[l*16 + 2*dp + 1];
        if (j < 16) { w0 *= QSCALE; w1 *= QSCALE; }
        ws[OFF_QKVW + i] = pack_rte(w0, w1);
    }
    for (int i = gid; i < 96; i += gs) {          // qkvB + ln1_b @ W, q pre-scaled
        int j = i % 48, l = i / 48;
        float a = qkv_b[i];
        for (int d = 0; d < 16; ++d) a += ln1_b[l*16+d] * qkv_w[(l*16+d)*48 + j];
        wsf[OFF_QKVB + i] = a * (j < 16 ? QSCALE : 1.0f);
    }
    for (int i = gid; i < 256; i += gs) {         // outW pairs over dd
        int dp = i & 7, dl = i >> 3, d = dl % 16, l = dl / 16;
        ws[OFF_OUTW + i] = pack_rte(out_w[l*256 + (2*dp)*16 + d],
                                    out_w[l*256 + (2*dp+1)*16 + d]);
    }
    for (int i = gid; i < 32; i += gs) wsf[OFF_OUTB + i] = out_b[i];
    for (int i = gid; i < 2048; i += gs) {        // c2hW pairs over d
        int dp = i & 7, o = i >> 3;
        ws[OFF_C2HW + i] = pack_rte(c2h_w[(2*dp)*256 + o], c2h_w[(2*dp+1)*256 + o]);
    }
    for (int i = gid; i < 256; i += gs) wsf[OFF_C2HB + i] = c2h_b[i];
    for (int i = gid; i < 768; i += gs) {         // fbte = fb + te[role]
        int d = i & 15, f = i >> 4;
        wsf[OFF_FBTE + i] = fb[f*16 + d] + te[role[f]*16 + d];
    }
    // F1A: W1^T A-frags (16x16x32: row=j=lane&15 (+16mt), k=dim=(lane>>4)*8+i; k>=16 zero)
    for (int i = gid; i < 2048; i += gs) {
        int dw = i & 3, lane = (i >> 2) & 63, mt = (i >> 8) & 3, l = i >> 10;
        int g = lane >> 4, j = 16*mt + (lane & 15);
        unsigned v = 0;
        if (g < 2) {
            int d0 = 8*g + 2*dw;
            v = pack_rte(ff1_w[l*1024 + d0*64 + j]     * ln2_s[l*16 + d0],
                         ff1_w[l*1024 + (d0+1)*64 + j] * ln2_s[l*16 + d0+1]);
        }
        ws[OFF_F1A + i] = v;
    }
    // F2A: W2^T A-frags (16x16x32: row=dim=lane&15, k=j=(lane>>4)*8+i (+32kf))
    for (int i = gid; i < 1024; i += gs) {
        int dw = i & 3, lane = (i >> 2) & 63, kf = (i >> 8) & 1, l = i >> 9;
        int dim = lane & 15, j0 = 32*kf + 8*(lane >> 4) + 2*dw;
        ws[OFF_F2A + i] = pack_rte(ff2_w[l*1024 + j0*16 + dim],
                                   ff2_w[l*1024 + (j0+1)*16 + dim]);
    }
    // B1V: b1' = ff1_b + ln2_b @ ff1_w, in C-frag order (row j=(lane>>4)*4+r+16mt)
    for (int i = gid; i < 2048; i += gs) {
        int r = i & 3, lane = (i >> 2) & 63, mt = (i >> 8) & 3, l = i >> 10;
        int j = 16*mt + (lane >> 4)*4 + r;
        float a = ff1_b[l*64 + j];
        for (int d = 0; d < 16; ++d) a += ln2_b[l*16+d] * ff1_w[l*1024 + d*64 + j];
        wsf[OFF_B1V + i] = a;
    }
    // B2V: b2 in C-frag order (row dim=(lane>>4)*4+r)
    for (int i = gid; i < 512; i += gs) {
        int r = i & 3, lane = (i >> 2) & 63, l = i >> 8;
        wsf[OFF_B2V + i] = ff2_b[l*16 + (lane >> 4)*4 + r];
    }
}

// Per-seq LDS for attention (unchanged from R4/R5).
struct __align__(16) SeqSh {
    uint4 Kp[50][3];
    uint4 Vp[25][5];
    unsigned clsP[8];
};

__global__ __launch_bounds__(256)
void enc_kernel(const float* __restrict__ cf,  const float* __restrict__ fe,
                const float* __restrict__ cls_tok,
                const unsigned* __restrict__ wsp, float* __restrict__ out)
{
    const unsigned ut = threadIdx.x;
    const int seq = ut / 49u;
    const int row = ut - seq * 49u;
    const int n0  = blockIdx.x * NS;
    const int n   = n0 + seq;
    const bool act = (seq < NS) && (n < NTOT);
    const int b = n >> 9, c = n & 511;

    __shared__ SeqSh S[NS];
    __shared__ __align__(16) unsigned Gbuf[4 * 32 * 36];  // per-wave FF scratch (18.4 KB)
    const float* wsf = (const float*)wsp;
    const h2 ONE = PK(1.f, 1.f);

    // ---- embedding ----
    float x[16];
    if (act) {
        if (row == 0) {
            #pragma unroll
            for (int d = 0; d < 16; ++d) x[d] = cls_tok[d];
        } else {
            const int f = row - 1;
            const float s = cf[((long)b * Fc + f) * Cc + c];
            const float4* fep = (const float4*)(fe + f*16);
            const float4* fbp = (const float4*)(wsf + OFF_FBTE + f*16);
            #pragma unroll
            for (int j = 0; j < 4; ++j) {
                float4 e = fep[j], t4 = fbp[j];
                x[4*j+0] = fmaf(s, e.x, t4.x); x[4*j+1] = fmaf(s, e.y, t4.y);
                x[4*j+2] = fmaf(s, e.z, t4.z); x[4*j+3] = fmaf(s, e.w, t4.w);
            }
        }
    } else {
        #pragma unroll
        for (int d = 0; d < 16; ++d) x[d] = 0.f;
    }

    for (int l = 0; l < 2; ++l) {
        h2 hp[8], qp[8];
        // ---- LN1 (scale/bias folded into qkv weights) ----
        if (act) {
            float mu = 0.f;
            #pragma unroll
            for (int d = 0; d < 16; ++d) mu += x[d];
            mu *= 0.0625f;
            float var = 0.f;
            #pragma unroll
            for (int d = 0; d < 16; ++d) { float dv = x[d]-mu; var = fmaf(dv,dv,var); }
            const float rr = rsqrtf(var*0.0625f + 1e-5f);
            const float nb = -mu * rr;
            #pragma unroll
            for (int p = 0; p < 8; ++p)
                hp[p] = PK(fmaf(x[2*p], rr, nb), fmaf(x[2*p+1], rr, nb));

            // ---- QKV via dot2 (weights uniform -> scalar loads) ----
            const unsigned* W = wsp + OFF_QKVW + l*384;
            const float* Bb = wsf + OFF_QKVB + l*48;
            #pragma unroll
            for (int j = 0; j < 16; j += 2) {      // q (pre-scaled)
                float a0 = Bb[j], a1 = Bb[j+1];
                #pragma unroll
                for (int dp = 0; dp < 8; ++dp) {
                    a0 = DOT2(hp[dp], U2H(W[ j   *8+dp]), a0);
                    a1 = DOT2(hp[dp], U2H(W[(j+1)*8+dp]), a1);
                }
                qp[j>>1] = PK(a0, a1);
            }
            unsigned kdw[8];
            #pragma unroll
            for (int j = 0; j < 16; j += 2) {      // k
                float a0 = Bb[16+j], a1 = Bb[17+j];
                #pragma unroll
                for (int dp = 0; dp < 8; ++dp) {
                    a0 = DOT2(hp[dp], U2H(W[(16+j)*8+dp]), a0);
                    a1 = DOT2(hp[dp], U2H(W[(17+j)*8+dp]), a1);
                }
                kdw[j>>1] = H2U(PK(a0, a1));
            }
            float vf[16];
            #pragma unroll
            for (int j = 0; j < 16; ++j) {         // v
                float a = Bb[32+j];
                #pragma unroll
                for (int dp = 0; dp < 8; ++dp)
                    a = DOT2(hp[dp], U2H(W[(32+j)*8+dp]), a);
                vf[j] = a;
            }
            S[seq].Kp[row][0] = make_uint4(kdw[0],kdw[1],kdw[2],kdw[3]);
            S[seq].Kp[row][1] = make_uint4(kdw[4],kdw[5],kdw[6],kdw[7]);
            if (row < 48) {
                _Float16* vh = (_Float16*)&S[seq].Vp[row>>1][0];
                const int pr = row & 1;
                #pragma unroll
                for (int d = 0; d < 16; ++d) vh[2*d + pr] = (_Float16)vf[d];
            } else {   // row 48 owns pair 24 fully; key 49 half = 0
                unsigned* vw = (unsigned*)&S[seq].Vp[24][0];
                #pragma unroll
                for (int d = 0; d < 16; ++d) vw[d] = H2U(PK(vf[d], 0.f));
            }
            if (row == 0) {
                const uint4 z = make_uint4(0,0,0,0);
                S[seq].Kp[49][0] = z; S[seq].Kp[49][1] = z;
            }
        }
        __syncthreads();   // K/V tile ready

        if (act) {
            // ---- attention: key-pair loop, no-max softmax in exp2 domain ----
            float ctx[16];
            #pragma unroll
            for (int d = 0; d < 16; ++d) ctx[d] = 0.f;
            float ls0=0.f, ls1=0.f, ls2=0.f, ls3=0.f;
            #pragma unroll 5
            for (int kp = 0; kp < 25; ++kp) {
                const uint4 ka0 = S[seq].Kp[2*kp  ][0], ka1 = S[seq].Kp[2*kp  ][1];
                const uint4 kb0 = S[seq].Kp[2*kp+1][0], kb1 = S[seq].Kp[2*kp+1][1];
                float sa0 = DOT2(qp[0],U2H(ka0.x), DOT2(qp[1],U2H(ka0.y), 0.f));
                float sb0 = DOT2(qp[0],U2H(kb0.x), DOT2(qp[1],U2H(kb0.y), 0.f));
                float sa1 = DOT2(qp[2],U2H(ka0.z), DOT2(qp[3],U2H(ka0.w), 0.f));
                float sb1 = DOT2(qp[2],U2H(kb0.z), DOT2(qp[3],U2H(kb0.w), 0.f));
                float sa2 = DOT2(qp[4],U2H(ka1.x), DOT2(qp[5],U2H(ka1.y), 0.f));
                float sb2 = DOT2(qp[4],U2H(kb1.x), DOT2(qp[5],U2H(kb1.y), 0.f));
                float sa3 = DOT2(qp[6],U2H(ka1.z), DOT2(qp[7],U2H(ka1.w), 0.f));
                float sb3 = DOT2(qp[6],U2H(kb1.z), DOT2(qp[7],U2H(kb1.w), 0.f));
                const h2 pp0 = PK(EXP2(sa0), EXP2(sb0));
                const h2 pp1 = PK(EXP2(sa1), EXP2(sb1));
                const h2 pp2 = PK(EXP2(sa2), EXP2(sb2));
                const h2 pp3 = PK(EXP2(sa3), EXP2(sb3));
                ls0 = DOT2(pp0, ONE, ls0); ls1 = DOT2(pp1, ONE, ls1);
                ls2 = DOT2(pp2, ONE, ls2); ls3 = DOT2(pp3, ONE, ls3);
                const uint4 v0 = S[seq].Vp[kp][0], v1 = S[seq].Vp[kp][1];
                const uint4 v2 = S[seq].Vp[kp][2], v3 = S[seq].Vp[kp][3];
                ctx[ 0]=DOT2(pp0,U2H(v0.x),ctx[ 0]); ctx[ 1]=DOT2(pp0,U2H(v0.y),ctx[ 1]);
                ctx[ 2]=DOT2(pp0,U2H(v0.z),ctx[ 2]); ctx[ 3]=DOT2(pp0,U2H(v0.w),ctx[ 3]);
                ctx[ 4]=DOT2(pp1,U2H(v1.x),ctx[ 4]); ctx[ 5]=DOT2(pp1,U2H(v1.y),ctx[ 5]);
                ctx[ 6]=DOT2(pp1,U2H(v1.z),ctx[ 6]); ctx[ 7]=DOT2(pp1,U2H(v1.w),ctx[ 7]);
                ctx[ 8]=DOT2(pp2,U2H(v2.x),ctx[ 8]); ctx[ 9]=DOT2(pp2,U2H(v2.y),ctx[ 9]);
                ctx[10]=DOT2(pp2,U2H(v2.z),ctx[10]); ctx[11]=DOT2(pp2,U2H(v2.w),ctx[11]);
                ctx[12]=DOT2(pp3,U2H(v3.x),ctx[12]); ctx[13]=DOT2(pp3,U2H(v3.y),ctx[13]);
                ctx[14]=DOT2(pp3,U2H(v3.z),ctx[14]); ctx[15]=DOT2(pp3,U2H(v3.w),ctx[15]);
            }
            // pad key 49 contributed exp2(0)=1 per head
            ls0 -= 1.f; ls1 -= 1.f; ls2 -= 1.f; ls3 -= 1.f;
            const float i0 = RCP(ls0), i1 = RCP(ls1), i2 = RCP(ls2), i3 = RCP(ls3);
            #pragma unroll
            for (int d = 0; d < 4;  ++d) ctx[d] *= i0;
            #pragma unroll
            for (int d = 4; d < 8;  ++d) ctx[d] *= i1;
            #pragma unroll
            for (int d = 8; d < 12; ++d) ctx[d] *= i2;
            #pragma unroll
            for (int d = 12; d < 16; ++d) ctx[d] *= i3;

            // ---- out-proj + residual ----
            h2 cp[8];
            #pragma unroll
            for (int p = 0; p < 8; ++p) cp[p] = PK(ctx[2*p], ctx[2*p+1]);
            const unsigned* OW = wsp + OFF_OUTW + l*128;
            const float* OB = wsf + OFF_OUTB + l*16;
            #pragma unroll
            for (int d = 0; d < 16; ++d) {
                float a = OB[d];
                #pragma unroll
                for (int dp = 0; dp < 8; ++dp) a = DOT2(cp[dp], U2H(OW[d*8+dp]), a);
                x[d] += a;
            }
        }

        // ---- LN2 (ALL lanes: FF MFMA needs every lane defined; folds in W1/b1) ----
        {
            float mu = 0.f;
            #pragma unroll
            for (int d = 0; d < 16; ++d) mu += x[d];
            mu *= 0.0625f;
            float var = 0.f;
            #pragma unroll
            for (int d = 0; d < 16; ++d) { float dv = x[d]-mu; var = fmaf(dv,dv,var); }
            const float rr = rsqrtf(var*0.0625f + 1e-5f);
            const float nb = -mu * rr;
            #pragma unroll
            for (int p = 0; p < 8; ++p)
                hp[p] = PK(fmaf(x[2*p], rr, nb), fmaf(x[2*p+1], rr, nb));
        }

        // ---- FF via MFMA, transposed dataflow (tokens stay in lanes) ----
        // FF1': D1[j][tok] = W1^T @ H^T (16x16x32, K=16 zero-padded), gelu on frags,
        // G (f16 pairs, per-wave LDS) -> FF2': D2[d][tok] = W2^T @ G (K=64, 2 kf),
        // Sb (aliased) transposes D2 back to row-per-lane for the exact f32 residual.
        {
            const int L   = (int)(ut & 63u);
            const int wv  = (int)(ut >> 6u);
            const int g4  = L >> 4;
            const int l15 = L & 15;
            unsigned* Gw  = Gbuf + wv * (32*36);
            float*    Sbw = (float*)Gw;          // alias; ordering hand-verified

            const uint4* f1a = (const uint4*)(wsp + OFF_F1A + l*1024);
            f16x8 A1[4];
            #pragma unroll
            for (int mt = 0; mt < 4; ++mt)
                A1[mt] = __builtin_bit_cast(f16x8, f1a[mt*64 + L]);
            const uint4* f2a = (const uint4*)(wsp + OFF_F2A + l*512);
            const f16x8 A20 = __builtin_bit_cast(f16x8, f2a[L]);
            const f16x8 A21 = __builtin_bit_cast(f16x8, f2a[64 + L]);
            const f32x4* b1p = (const f32x4*)(wsf + OFF_B1V + l*1024);
            f32x4 C1[4];
            #pragma unroll
            for (int mt = 0; mt < 4; ++mt) C1[mt] = b1p[mt*64 + L];
            const f32x4 Cb2 = ((const f32x4*)(wsf + OFF_B2V + l*256))[L];

            #pragma unroll
            for (int ct = 0; ct < 2; ++ct) {      // 32-token column tiles
                // FF1' + gelu + G write
                #pragma unroll
                for (int tt = 0; tt < 2; ++tt) {
                    const int src = 32*ct + 16*tt + l15;
                    unsigned bw0, bw1, bw2, bw3;
                    {
                        unsigned lo0 = __shfl(H2U(hp[0]), src), hh0 = __shfl(H2U(hp[4]), src);
                        unsigned lo1 = __shfl(H2U(hp[1]), src), hh1 = __shfl(H2U(hp[5]), src);
                        unsigned lo2 = __shfl(H2U(hp[2]), src), hh2 = __shfl(H2U(hp[6]), src);
                        unsigned lo3 = __shfl(H2U(hp[3]), src), hh3 = __shfl(H2U(hp[7]), src);
                        bw0 = (g4 == 0) ? lo0 : (g4 == 1) ? hh0 : 0u;
                        bw1 = (g4 == 0) ? lo1 : (g4 == 1) ? hh1 : 0u;
                        bw2 = (g4 == 0) ? lo2 : (g4 == 1) ? hh2 : 0u;
                        bw3 = (g4 == 0) ? lo3 : (g4 == 1) ? hh3 : 0u;
                    }
                    const f16x8 Bf = __builtin_bit_cast(f16x8, make_uint4(bw0, bw1, bw2, bw3));
                    #pragma unroll
                    for (int mt = 0; mt < 4; ++mt) {
                        f32x4 Dq = MFMA16(A1[mt], Bf, C1[mt]);
                        const float e0 = gelu1(Dq[0]), e1 = gelu1(Dq[1]);
                        const float e2 = gelu1(Dq[2]), e3 = gelu1(Dq[3]);
                        uint2 wv2;
                        wv2.x = H2U(PK(e0, e1));
                        wv2.y = H2U(PK(e2, e3));
                        *(uint2*)(Gw + (16*tt + l15)*36 + 8*mt + 2*g4) = wv2;
                    }
                }
                // FF2' (K=64 via 2 kf) + Sb transpose write
                #pragma unroll
                for (int sub = 0; sub < 2; ++sub) {
                    const unsigned* gr = Gw + (16*sub + l15)*36 + 4*g4;
                    const f16x8 B0 = __builtin_bit_cast(f16x8, *(const uint4*)gr);
                    const f16x8 B1 = __builtin_bit_cast(f16x8, *(const uint4*)(gr + 16));
                    f32x4 t = MFMA16(A20, B0, Cb2);
                    t = MFMA16(A21, B1, t);
                    *(f32x4*)(Sbw + (16*sub + l15)*20 + 4*g4) = t;
                }
                // residual add for this tile's tokens (half-wave)
                if ((L >> 5) == ct) {
                    const float* sr = Sbw + (L & 31)*20;
                    #pragma unroll
                    for (int k4 = 0; k4 < 16; ++k4) x[k4] += sr[k4];
                }
            }
        }
        __syncthreads();   // attn readers done before next layer overwrites LDS
    }

    // ---- head: cls row packed to LDS, lane ut owns output col o = ut ----
    if (act && row == 0) {
        #pragma unroll
        for (int p = 0; p < 8; ++p) S[seq].clsP[p] = H2U(PK(x[2*p], x[2*p+1]));
    }
    __syncthreads();

    const uint4* cw = (const uint4*)(wsp + OFF_C2HW + ut*8);
    const uint4 w0 = cw[0], w1 = cw[1];
    const float bt = wsf[OFF_C2HB + ut];
    #pragma unroll
    for (int oo = 0; oo < NS; ++oo) {
        const int n2 = n0 + oo;
        if (n2 < NTOT) {
            float a = bt;
            a = DOT2(U2H(S[oo].clsP[0]), U2H(w0.x), a);
            a = DOT2(U2H(S[oo].clsP[1]), U2H(w0.y), a);
            a = DOT2(U2H(S[oo].clsP[2]), U2H(w0.z), a);
            a = DOT2(U2H(S[oo].clsP[3]), U2H(w0.w), a);
            a = DOT2(U2H(S[oo].clsP[4]), U2H(w1.x), a);
            a = DOT2(U2H(S[oo].clsP[5]), U2H(w1.y), a);
            a = DOT2(U2H(S[oo].clsP[6]), U2H(w1.z), a);
            a = DOT2(U2H(S[oo].clsP[7]), U2H(w1.w), a);
            out[((long)(n2 >> 9) * 256 + ut) * 512 + (n2 & 511)] = a;
        }
    }
}

extern "C" void kernel_launch(void* const* d_in, const int* in_sizes, int n_in,
                              void* d_out, int out_size, void* d_ws, size_t ws_size,
                              hipStream_t stream) {
    const float* cf       = (const float*)d_in[0];
    const float* fe       = (const float*)d_in[1];
    const float* fb       = (const float*)d_in[2];
    const float* cls_tok  = (const float*)d_in[3];
    const float* te       = (const float*)d_in[4];
    const int*   role_ids = (const int*)  d_in[5];
    const float* ln1_s    = (const float*)d_in[6];
    const float* ln1_b    = (const float*)d_in[7];
    const float* qkv_w    = (const float*)d_in[8];
    const float* qkv_b    = (const float*)d_in[9];
    const float* out_w    = (const float*)d_in[10];
    const float* out_b    = (const float*)d_in[11];
    const float* ln2_s    = (const float*)d_in[12];
    const float* ln2_b    = (const float*)d_in[13];
    const float* ff1_w    = (const float*)d_in[14];
    const float* ff1_b    = (const float*)d_in[15];
    const float* ff2_w    = (const float*)d_in[16];
    const float* ff2_b    = (const float*)d_in[17];
    const float* c2h_w    = (const float*)d_in[18];
    const float* c2h_b    = (const float*)d_in[19];
    float* out = (float*)d_out;
    unsigned* ws = (unsigned*)d_ws;

    pack_kernel<<<16, 256, 0, stream>>>(qkv_w, qkv_b, out_w, out_b, ff1_w, ff1_b,
                                        ff2_w, ff2_b, c2h_w, c2h_b, fb, te,
                                        role_ids, ln1_s, ln1_b, ln2_s, ln2_b, ws);
    enc_kernel<<<NBLK, 256, 0, stream>>>(cf, fe, cls_tok, ws, out);
}

// Round 7
// 392.588 us; speedup vs baseline: 1.3625x; 1.0639x over previous
//
#include <hip/hip_runtime.h>
#include <math.h>

// Problem constants
#define Bc    64
#define Cc    512
#define Fc    48
#define NTOT  32768
#define TT    49
#define NS    5            // sequences per 256-thread block
#define NBLK  ((NTOT + NS - 1) / NS)   // 6554 blocks
// attn scale 0.5 * log2(e) folded into q weights/bias at pack time
#define QSCALE 0.72134752044448169f
// gelu(g) ~= g / (1 + exp2(C1*g + C2*g^3))  (validated R2-R6)
#define GC1 (-2.3022082f)
#define GC2 (-0.10294324f)

#define EXP2(x) __builtin_amdgcn_exp2f(x)
#define RCP(x)  __builtin_amdgcn_rcpf(x)

using h2 = decltype(__builtin_amdgcn_cvt_pkrtz(0.f, 0.f));   // v2f16
typedef _Float16 f16x8 __attribute__((ext_vector_type(8)));
typedef float    f32x4 __attribute__((ext_vector_type(4)));

#define MFMA16(a,b,c) __builtin_amdgcn_mfma_f32_16x16x32_f16((a),(b),(c),0,0,0)

__device__ __forceinline__ h2 PK(float a, float b) {         // round-toward-zero pack
    return __builtin_amdgcn_cvt_pkrtz(a, b);
}
__device__ __forceinline__ unsigned H2U(h2 h) { return __builtin_bit_cast(unsigned, h); }
__device__ __forceinline__ h2 U2H(unsigned u) { return __builtin_bit_cast(h2, u); }

__device__ __forceinline__ float DOT2(h2 a, h2 b, float c) {
#if __has_builtin(__builtin_amdgcn_fdot2)
    return __builtin_amdgcn_fdot2(a, b, c, false);   // fp32 accumulate
#else
    return fmaf((float)a[0], (float)b[0], fmaf((float)a[1], (float)b[1], c));
#endif
}
__device__ __forceinline__ unsigned pack_rte(float a, float b) {  // accurate pack (setup)
    h2 h; h[0] = (_Float16)a; h[1] = (_Float16)b;
    return __builtin_bit_cast(unsigned, h);
}
__device__ __forceinline__ float gelu1(float g) {
    const float u = g * fmaf(GC2, g * g, GC1);
    return g * RCP(1.0f + EXP2(u));
}

// ---- ws dword offsets ----
#define OFF_OUTW 0        // [l][d<16][dp<8] h2 pairs over dd                       (256)
#define OFF_OUTB 256      // [l][16] f32                                            (32)
#define OFF_C2HW 288      // [o<256][dp<8] pairs over d                            (2048)
#define OFF_C2HB 2336     // [256] f32                                              (256)
#define OFF_FBTE 2592     // [f<48][d<16] f32 = fb + te[role]                       (768)
// FF MFMA operands (LN2-s folded into W1, LN2-b into b1):
#define OFF_F1A  3360     // [l][mt<4][lane<64][4dw] f16 pairs: W1^T A-frags      (2048)
#define OFF_F2A  5408     // [l][kf<2][lane<64][4dw] f16 pairs: W2^T A-frags      (1024)
#define OFF_B1V  6432     // [l][mt<4][lane<64][4]  f32: b1' C-frags              (2048)
#define OFF_B2V  8480     // [l][lane<64][4]        f32: b2 C-frags                (512)
// QKV MFMA operands (LN1-s folded; q cols pre-scaled by QSCALE):
#define OFF_QA   8992     // [l][mt<3][lane<64][4dw] f16 pairs: Wqkv^T A-frags    (1536)
#define OFF_QC   10528    // [l][mt<3][lane<64][4]  f32: folded bias C-frags      (1536)
#define WS_DWORDS 12064

__global__ __launch_bounds__(256)
void pack_kernel(const float* __restrict__ qkv_w, const float* __restrict__ qkv_b,
                 const float* __restrict__ out_w, const float* __restrict__ out_b,
                 const float* __restrict__ ff1_w, const float* __restrict__ ff1_b,
                 const float* __restrict__ ff2_w, const float* __restrict__ ff2_b,
                 const float* __restrict__ c2h_w, const float* __restrict__ c2h_b,
                 const float* __restrict__ fb,    const float* __restrict__ te,
                 const int*   __restrict__ role,
                 const float* __restrict__ ln1_s, const float* __restrict__ ln1_b,
                 const float* __restrict__ ln2_s, const float* __restrict__ ln2_b,
                 unsigned* __restrict__ ws)
{
    const int gid = blockIdx.x * 256 + threadIdx.x;
    const int gs  = gridDim.x * 256;
    float* wsf = (float*)ws;
    for (int i = gid; i < 256; i += gs) {         // outW pairs over dd
        int dp = i & 7, dl = i >> 3, d = dl % 16, l = dl / 16;
        ws[OFF_OUTW + i] = pack_rte(out_w[l*256 + (2*dp)*16 + d],
                                    out_w[l*256 + (2*dp+1)*16 + d]);
    }
    for (int i = gid; i < 32; i += gs) wsf[OFF_OUTB + i] = out_b[i];
    for (int i = gid; i < 2048; i += gs) {        // c2hW pairs over d
        int dp = i & 7, o = i >> 3;
        ws[OFF_C2HW + i] = pack_rte(c2h_w[(2*dp)*256 + o], c2h_w[(2*dp+1)*256 + o]);
    }
    for (int i = gid; i < 256; i += gs) wsf[OFF_C2HB + i] = c2h_b[i];
    for (int i = gid; i < 768; i += gs) {         // fbte = fb + te[role]
        int d = i & 15, f = i >> 4;
        wsf[OFF_FBTE + i] = fb[f*16 + d] + te[role[f]*16 + d];
    }
    // F1A: W1^T A-frags (row=j=lane&15 (+16mt), k=dim=(lane>>4)*8+i; k>=16 zero)
    for (int i = gid; i < 2048; i += gs) {
        int dw = i & 3, lane = (i >> 2) & 63, mt = (i >> 8) & 3, l = i >> 10;
        int g = lane >> 4, j = 16*mt + (lane & 15);
        unsigned v = 0;
        if (g < 2) {
            int d0 = 8*g + 2*dw;
            v = pack_rte(ff1_w[l*1024 + d0*64 + j]     * ln2_s[l*16 + d0],
                         ff1_w[l*1024 + (d0+1)*64 + j] * ln2_s[l*16 + d0+1]);
        }
        ws[OFF_F1A + i] = v;
    }
    // F2A: W2^T A-frags (row=dim=lane&15, k=j=(lane>>4)*8+i (+32kf))
    for (int i = gid; i < 1024; i += gs) {
        int dw = i & 3, lane = (i >> 2) & 63, kf = (i >> 8) & 1, l = i >> 9;
        int dim = lane & 15, j0 = 32*kf + 8*(lane >> 4) + 2*dw;
        ws[OFF_F2A + i] = pack_rte(ff2_w[l*1024 + j0*16 + dim],
                                   ff2_w[l*1024 + (j0+1)*16 + dim]);
    }
    // B1V: b1' = ff1_b + ln2_b @ ff1_w, C-frag order (row j=(lane>>4)*4+r+16mt)
    for (int i = gid; i < 2048; i += gs) {
        int r = i & 3, lane = (i >> 2) & 63, mt = (i >> 8) & 3, l = i >> 10;
        int j = 16*mt + (lane >> 4)*4 + r;
        float a = ff1_b[l*64 + j];
        for (int d = 0; d < 16; ++d) a += ln2_b[l*16+d] * ff1_w[l*1024 + d*64 + j];
        wsf[OFF_B1V + i] = a;
    }
    // B2V: b2 in C-frag order (row dim=(lane>>4)*4+r)
    for (int i = gid; i < 512; i += gs) {
        int r = i & 3, lane = (i >> 2) & 63, l = i >> 8;
        wsf[OFF_B2V + i] = ff2_b[l*16 + (lane >> 4)*4 + r];
    }
    // QA: Wqkv^T A-frags (row=j=lane&15 (+16mt), k=dim=(lane>>4)*8+i; k>=16 zero)
    for (int i = gid; i < 1536; i += gs) {
        int dw = i & 3, t = i >> 2, lane = t & 63, t2 = t >> 6, mt = t2 % 3, l = t2 / 3;
        int g = lane >> 4, j = 16*mt + (lane & 15);
        unsigned v = 0;
        if (g < 2) {
            int d0 = 8*g + 2*dw;
            float w0 = qkv_w[(l*16+d0)*48 + j]   * ln1_s[l*16+d0];
            float w1 = qkv_w[(l*16+d0+1)*48 + j] * ln1_s[l*16+d0+1];
            if (mt == 0) { w0 *= QSCALE; w1 *= QSCALE; }
            v = pack_rte(w0, w1);
        }
        ws[OFF_QA + i] = v;
    }
    // QC: folded bias (qkv_b + ln1_b @ qkv_w), C-frag order, q cols scaled
    for (int i = gid; i < 1536; i += gs) {
        int r = i & 3, t = i >> 2, lane = t & 63, t2 = t >> 6, mt = t2 % 3, l = t2 / 3;
        int j = 16*mt + (lane >> 4)*4 + r;
        float a = qkv_b[l*48 + j];
        for (int d = 0; d < 16; ++d) a += ln1_b[l*16+d] * qkv_w[(l*16+d)*48 + j];
        if (mt == 0) a *= QSCALE;
        wsf[OFF_QC + i] = a;
    }
}

// Per-seq LDS for attention: K rows as f16 dim-pairs; V as f16 key-pair dwords.
struct __align__(16) SeqSh {
    uint4 Kp[50][3];
    uint4 Vp[25][5];
    unsigned clsP[8];
};

__global__ __launch_bounds__(256)
void enc_kernel(const float* __restrict__ cf,  const float* __restrict__ fe,
                const float* __restrict__ cls_tok,
                const unsigned* __restrict__ wsp, float* __restrict__ out)
{
    const unsigned ut = threadIdx.x;
    const int seq = ut / 49u;
    const int row = ut - seq * 49u;
    const int n0  = blockIdx.x * NS;
    const int n   = n0 + seq;
    const bool act = (seq < NS) && (n < NTOT);
    const int b = n >> 9, c = n & 511;
    const int L = (int)(ut & 63u), wv = (int)(ut >> 6u);
    const int g4 = L >> 4, l15 = L & 15;

    __shared__ SeqSh S[NS];
    __shared__ __align__(16) unsigned Gbuf[4 * 1152];  // per-wave scratch (18.4 KB)
    unsigned* Gw  = Gbuf + wv * 1152;
    unsigned* Hst = Gw;          // [64][10] dwords: staged hp (rows = wave-local token)
    unsigned* Qst = Gw + 640;    // [64][8]  dwords: Q transpose-back
    const float* wsf = (const float*)wsp;
    const h2 ONE = PK(1.f, 1.f);

    // ---- embedding ----
    float x[16];
    if (act) {
        if (row == 0) {
            #pragma unroll
            for (int d = 0; d < 16; ++d) x[d] = cls_tok[d];
        } else {
            const int f = row - 1;
            const float s = cf[((long)b * Fc + f) * Cc + c];
            const float4* fep = (const float4*)(fe + f*16);
            const float4* fbp = (const float4*)(wsf + OFF_FBTE + f*16);
            #pragma unroll
            for (int j = 0; j < 4; ++j) {
                float4 e = fep[j], t4 = fbp[j];
                x[4*j+0] = fmaf(s, e.x, t4.x); x[4*j+1] = fmaf(s, e.y, t4.y);
                x[4*j+2] = fmaf(s, e.z, t4.z); x[4*j+3] = fmaf(s, e.w, t4.w);
            }
        }
    } else {
        #pragma unroll
        for (int d = 0; d < 16; ++d) x[d] = 0.f;
    }

    for (int l = 0; l < 2; ++l) {
        h2 hp[8], qp[8];
        // ---- LN1, ALL lanes (scale/bias folded into QA/QC; pad lanes x=0 -> finite) ----
        {
            float mu = 0.f;
            #pragma unroll
            for (int d = 0; d < 16; ++d) mu += x[d];
            mu *= 0.0625f;
            float var = 0.f;
            #pragma unroll
            for (int d = 0; d < 16; ++d) { float dv = x[d]-mu; var = fmaf(dv,dv,var); }
            const float rr = rsqrtf(var*0.0625f + 1e-5f);
            const float nb = -mu * rr;
            #pragma unroll
            for (int p = 0; p < 8; ++p)
                hp[p] = PK(fmaf(x[2*p], rr, nb), fmaf(x[2*p+1], rr, nb));
        }
        // ---- H-stage write (per-wave, no barrier needed) ----
        #pragma unroll
        for (int j = 0; j < 4; ++j) {
            uint2 t; t.x = H2U(hp[2*j]); t.y = H2U(hp[2*j+1]);
            *(uint2*)(Hst + 10u*(unsigned)L + 2u*j) = t;
        }
        // ---- QKV via MFMA: D^T[j][tok] = Wqkv^T @ H^T, 3 j-tiles x 4 token-tiles ----
        {
            const uint4* qa  = (const uint4*)(wsp + OFF_QA + l*768);
            const f32x4* qcf = (const f32x4*)(wsf + OFF_QC + l*768);
            const f16x8 Aq = __builtin_bit_cast(f16x8, qa[L]);
            const f16x8 Ak = __builtin_bit_cast(f16x8, qa[64 + L]);
            const f16x8 Av = __builtin_bit_cast(f16x8, qa[128 + L]);
            const f32x4 Cq = qcf[L], Ck = qcf[64 + L], Cv = qcf[128 + L];
            #pragma unroll
            for (int tt = 0; tt < 4; ++tt) {
                const int trow = 16*tt + l15;
                uint2 b0 = make_uint2(0u,0u), b1 = make_uint2(0u,0u);
                if (g4 < 2) {
                    b0 = *(const uint2*)(Hst + 10u*trow + 4u*g4);
                    b1 = *(const uint2*)(Hst + 10u*trow + 4u*g4 + 2u);
                }
                const f16x8 Bf = __builtin_bit_cast(f16x8, make_uint4(b0.x,b0.y,b1.x,b1.y));
                const f32x4 Dq = MFMA16(Aq, Bf, Cq);
                const f32x4 Dk = MFMA16(Ak, Bf, Ck);
                const f32x4 Dv = MFMA16(Av, Bf, Cv);
                { uint2 t; t.x = H2U(PK(Dq[0],Dq[1])); t.y = H2U(PK(Dq[2],Dq[3]));
                  *(uint2*)(Qst + 8u*trow + 2u*g4) = t; }
                const int tok = 64*wv + trow;
                if (tok < 245) {
                    const int sq = (tok * 1338) >> 16;     // tok/49 for tok<=255
                    const int rw = tok - 49*sq;
                    { uint2 t; t.x = H2U(PK(Dk[0],Dk[1])); t.y = H2U(PK(Dk[2],Dk[3]));
                      *(uint2*)((unsigned*)&S[sq].Kp[rw][0] + 2u*g4) = t; }
                    _Float16* vh = (_Float16*)&S[sq].Vp[rw>>1][0];
                    const int pr = rw & 1;
                    vh[2*(4*g4+0)+pr] = (_Float16)Dv[0];
                    vh[2*(4*g4+1)+pr] = (_Float16)Dv[1];
                    vh[2*(4*g4+2)+pr] = (_Float16)Dv[2];
                    vh[2*(4*g4+3)+pr] = (_Float16)Dv[3];
                    if (rw == 48) {   // zero pad-key halves of Vp[24]
                        vh[2*(4*g4+0)+1] = (_Float16)0.f;
                        vh[2*(4*g4+1)+1] = (_Float16)0.f;
                        vh[2*(4*g4+2)+1] = (_Float16)0.f;
                        vh[2*(4*g4+3)+1] = (_Float16)0.f;
                    }
                }
            }
            // Q readback: lane's own token row (wave-local)
            #pragma unroll
            for (int j = 0; j < 4; ++j) {
                uint2 t = *(const uint2*)(Qst + 8u*(unsigned)L + 2u*j);
                qp[2*j] = U2H(t.x); qp[2*j+1] = U2H(t.y);
            }
        }
        __syncthreads();   // K/V tile ready

        if (act) {
            // ---- attention: 24 full key-pairs + peeled key 48, exp2-domain softmax ----
            float ctx[16];
            #pragma unroll
            for (int d = 0; d < 16; ++d) ctx[d] = 0.f;
            float ls0=0.f, ls1=0.f, ls2=0.f, ls3=0.f;
            #pragma unroll 4
            for (int kp = 0; kp < 24; ++kp) {
                const uint4 ka0 = S[seq].Kp[2*kp  ][0], ka1 = S[seq].Kp[2*kp  ][1];
                const uint4 kb0 = S[seq].Kp[2*kp+1][0], kb1 = S[seq].Kp[2*kp+1][1];
                float sa0 = DOT2(qp[0],U2H(ka0.x), DOT2(qp[1],U2H(ka0.y), 0.f));
                float sb0 = DOT2(qp[0],U2H(kb0.x), DOT2(qp[1],U2H(kb0.y), 0.f));
                float sa1 = DOT2(qp[2],U2H(ka0.z), DOT2(qp[3],U2H(ka0.w), 0.f));
                float sb1 = DOT2(qp[2],U2H(kb0.z), DOT2(qp[3],U2H(kb0.w), 0.f));
                float sa2 = DOT2(qp[4],U2H(ka1.x), DOT2(qp[5],U2H(ka1.y), 0.f));
                float sb2 = DOT2(qp[4],U2H(kb1.x), DOT2(qp[5],U2H(kb1.y), 0.f));
                float sa3 = DOT2(qp[6],U2H(ka1.z), DOT2(qp[7],U2H(ka1.w), 0.f));
                float sb3 = DOT2(qp[6],U2H(kb1.z), DOT2(qp[7],U2H(kb1.w), 0.f));
                const h2 pp0 = PK(EXP2(sa0), EXP2(sb0));
                const h2 pp1 = PK(EXP2(sa1), EXP2(sb1));
                const h2 pp2 = PK(EXP2(sa2), EXP2(sb2));
                const h2 pp3 = PK(EXP2(sa3), EXP2(sb3));
                ls0 = DOT2(pp0, ONE, ls0); ls1 = DOT2(pp1, ONE, ls1);
                ls2 = DOT2(pp2, ONE, ls2); ls3 = DOT2(pp3, ONE, ls3);
                const uint4 v0 = S[seq].Vp[kp][0], v1 = S[seq].Vp[kp][1];
                const uint4 v2 = S[seq].Vp[kp][2], v3 = S[seq].Vp[kp][3];
                ctx[ 0]=DOT2(pp0,U2H(v0.x),ctx[ 0]); ctx[ 1]=DOT2(pp0,U2H(v0.y),ctx[ 1]);
                ctx[ 2]=DOT2(pp0,U2H(v0.z),ctx[ 2]); ctx[ 3]=DOT2(pp0,U2H(v0.w),ctx[ 3]);
                ctx[ 4]=DOT2(pp1,U2H(v1.x),ctx[ 4]); ctx[ 5]=DOT2(pp1,U2H(v1.y),ctx[ 5]);
                ctx[ 6]=DOT2(pp1,U2H(v1.z),ctx[ 6]); ctx[ 7]=DOT2(pp1,U2H(v1.w),ctx[ 7]);
                ctx[ 8]=DOT2(pp2,U2H(v2.x),ctx[ 8]); ctx[ 9]=DOT2(pp2,U2H(v2.y),ctx[ 9]);
                ctx[10]=DOT2(pp2,U2H(v2.z),ctx[10]); ctx[11]=DOT2(pp2,U2H(v2.w),ctx[11]);
                ctx[12]=DOT2(pp3,U2H(v3.x),ctx[12]); ctx[13]=DOT2(pp3,U2H(v3.y),ctx[13]);
                ctx[14]=DOT2(pp3,U2H(v3.z),ctx[14]); ctx[15]=DOT2(pp3,U2H(v3.w),ctx[15]);
            }
            {   // peeled: key 48 real, key 49 absent (p_hi = 0)
                const uint4 ka0 = S[seq].Kp[48][0], ka1 = S[seq].Kp[48][1];
                float sa0 = DOT2(qp[0],U2H(ka0.x), DOT2(qp[1],U2H(ka0.y), 0.f));
                float sa1 = DOT2(qp[2],U2H(ka0.z), DOT2(qp[3],U2H(ka0.w), 0.f));
                float sa2 = DOT2(qp[4],U2H(ka1.x), DOT2(qp[5],U2H(ka1.y), 0.f));
                float sa3 = DOT2(qp[6],U2H(ka1.z), DOT2(qp[7],U2H(ka1.w), 0.f));
                const h2 pp0 = PK(EXP2(sa0), 0.f);
                const h2 pp1 = PK(EXP2(sa1), 0.f);
                const h2 pp2 = PK(EXP2(sa2), 0.f);
                const h2 pp3 = PK(EXP2(sa3), 0.f);
                ls0 = DOT2(pp0, ONE, ls0); ls1 = DOT2(pp1, ONE, ls1);
                ls2 = DOT2(pp2, ONE, ls2); ls3 = DOT2(pp3, ONE, ls3);
                const uint4 v0 = S[seq].Vp[24][0], v1 = S[seq].Vp[24][1];
                const uint4 v2 = S[seq].Vp[24][2], v3 = S[seq].Vp[24][3];
                ctx[ 0]=DOT2(pp0,U2H(v0.x),ctx[ 0]); ctx[ 1]=DOT2(pp0,U2H(v0.y),ctx[ 1]);
                ctx[ 2]=DOT2(pp0,U2H(v0.z),ctx[ 2]); ctx[ 3]=DOT2(pp0,U2H(v0.w),ctx[ 3]);
                ctx[ 4]=DOT2(pp1,U2H(v1.x),ctx[ 4]); ctx[ 5]=DOT2(pp1,U2H(v1.y),ctx[ 5]);
                ctx[ 6]=DOT2(pp1,U2H(v1.z),ctx[ 6]); ctx[ 7]=DOT2(pp1,U2H(v1.w),ctx[ 7]);
                ctx[ 8]=DOT2(pp2,U2H(v2.x),ctx[ 8]); ctx[ 9]=DOT2(pp2,U2H(v2.y),ctx[ 9]);
                ctx[10]=DOT2(pp2,U2H(v2.z),ctx[10]); ctx[11]=DOT2(pp2,U2H(v2.w),ctx[11]);
                ctx[12]=DOT2(pp3,U2H(v3.x),ctx[12]); ctx[13]=DOT2(pp3,U2H(v3.y),ctx[13]);
                ctx[14]=DOT2(pp3,U2H(v3.z),ctx[14]); ctx[15]=DOT2(pp3,U2H(v3.w),ctx[15]);
            }
            const float i0 = RCP(ls0), i1 = RCP(ls1), i2 = RCP(ls2), i3 = RCP(ls3);
            #pragma unroll
            for (int d = 0; d < 4;  ++d) ctx[d] *= i0;
            #pragma unroll
            for (int d = 4; d < 8;  ++d) ctx[d] *= i1;
            #pragma unroll
            for (int d = 8; d < 12; ++d) ctx[d] *= i2;
            #pragma unroll
            for (int d = 12; d < 16; ++d) ctx[d] *= i3;

            // ---- out-proj + residual (dot2) ----
            h2 cp[8];
            #pragma unroll
            for (int p = 0; p < 8; ++p) cp[p] = PK(ctx[2*p], ctx[2*p+1]);
            const unsigned* OW = wsp + OFF_OUTW + l*128;
            const float* OB = wsf + OFF_OUTB + l*16;
            #pragma unroll
            for (int d = 0; d < 16; ++d) {
                float a = OB[d];
                #pragma unroll
                for (int dp = 0; dp < 8; ++dp) a = DOT2(cp[dp], U2H(OW[d*8+dp]), a);
                x[d] += a;
            }
        }

        // ---- LN2 ALL lanes (folds in F1A/B1V) ----
        {
            float mu = 0.f;
            #pragma unroll
            for (int d = 0; d < 16; ++d) mu += x[d];
            mu *= 0.0625f;
            float var = 0.f;
            #pragma unroll
            for (int d = 0; d < 16; ++d) { float dv = x[d]-mu; var = fmaf(dv,dv,var); }
            const float rr = rsqrtf(var*0.0625f + 1e-5f);
            const float nb = -mu * rr;
            #pragma unroll
            for (int p = 0; p < 8; ++p)
                hp[p] = PK(fmaf(x[2*p], rr, nb), fmaf(x[2*p+1], rr, nb));
        }
        // ---- H-stage rewrite + pre-read all 4 FF B-frags (G buffer aliases Hst) ----
        #pragma unroll
        for (int j = 0; j < 4; ++j) {
            uint2 t; t.x = H2U(hp[2*j]); t.y = H2U(hp[2*j+1]);
            *(uint2*)(Hst + 10u*(unsigned)L + 2u*j) = t;
        }
        uint4 BfFF[4];
        #pragma unroll
        for (int q = 0; q < 4; ++q) {
            uint2 b0 = make_uint2(0u,0u), b1 = make_uint2(0u,0u);
            if (g4 < 2) {
                b0 = *(const uint2*)(Hst + 10u*(16*q + l15) + 4u*g4);
                b1 = *(const uint2*)(Hst + 10u*(16*q + l15) + 4u*g4 + 2u);
            }
            BfFF[q] = make_uint4(b0.x, b0.y, b1.x, b1.y);
        }

        // ---- FF via MFMA (transposed dataflow, tokens in lanes) ----
        {
            unsigned* Gw2 = Gw;                  // G gelu buffer [32][36] (aliases Hst/Qst)
            float*    Sbw = (float*)Gw;          // Sb alias; ordering hand-verified

            const uint4* f1a = (const uint4*)(wsp + OFF_F1A + l*1024);
            f16x8 A1[4];
            #pragma unroll
            for (int mt = 0; mt < 4; ++mt)
                A1[mt] = __builtin_bit_cast(f16x8, f1a[mt*64 + L]);
            const uint4* f2a = (const uint4*)(wsp + OFF_F2A + l*512);
            const f16x8 A20 = __builtin_bit_cast(f16x8, f2a[L]);
            const f16x8 A21 = __builtin_bit_cast(f16x8, f2a[64 + L]);
            const f32x4* b1p = (const f32x4*)(wsf + OFF_B1V + l*1024);
            f32x4 C1[4];
            #pragma unroll
            for (int mt = 0; mt < 4; ++mt) C1[mt] = b1p[mt*64 + L];
            const f32x4 Cb2 = ((const f32x4*)(wsf + OFF_B2V + l*256))[L];

            #pragma unroll
            for (int ct = 0; ct < 2; ++ct) {      // 32-token column tiles
                #pragma unroll
                for (int tt = 0; tt < 2; ++tt) {
                    const f16x8 Bf = __builtin_bit_cast(f16x8, BfFF[2*ct + tt]);
                    #pragma unroll
                    for (int mt = 0; mt < 4; ++mt) {
                        f32x4 Dq = MFMA16(A1[mt], Bf, C1[mt]);
                        const float e0 = gelu1(Dq[0]), e1 = gelu1(Dq[1]);
                        const float e2 = gelu1(Dq[2]), e3 = gelu1(Dq[3]);
                        uint2 wv2;
                        wv2.x = H2U(PK(e0, e1));
                        wv2.y = H2U(PK(e2, e3));
                        *(uint2*)(Gw2 + (16*tt + l15)*36 + 8*mt + 2*g4) = wv2;
                    }
                }
                #pragma unroll
                for (int sub = 0; sub < 2; ++sub) {
                    const unsigned* gr = Gw2 + (16*sub + l15)*36 + 4*g4;
                    const f16x8 B0 = __builtin_bit_cast(f16x8, *(const uint4*)gr);
                    const f16x8 B1 = __builtin_bit_cast(f16x8, *(const uint4*)(gr + 16));
                    f32x4 t = MFMA16(A20, B0, Cb2);
                    t = MFMA16(A21, B1, t);
                    *(f32x4*)(Sbw + (16*sub + l15)*20 + 4*g4) = t;
                }
                if ((L >> 5) == ct) {
                    const float* sr = Sbw + (L & 31)*20;
                    #pragma unroll
                    for (int k4 = 0; k4 < 16; ++k4) x[k4] += sr[k4];
                }
            }
        }
        __syncthreads();   // attn readers done before next layer overwrites LDS
    }

    // ---- head: cls row packed to LDS, lane ut owns output col o = ut ----
    if (act && row == 0) {
        #pragma unroll
        for (int p = 0; p < 8; ++p) S[seq].clsP[p] = H2U(PK(x[2*p], x[2*p+1]));
    }
    __syncthreads();

    const uint4* cw = (const uint4*)(wsp + OFF_C2HW + ut*8);
    const uint4 w0 = cw[0], w1 = cw[1];
    const float bt = wsf[OFF_C2HB + ut];
    #pragma unroll
    for (int oo = 0; oo < NS; ++oo) {
        const int n2 = n0 + oo;
        if (n2 < NTOT) {
            float a = bt;
            a = DOT2(U2H(S[oo].clsP[0]), U2H(w0.x), a);
            a = DOT2(U2H(S[oo].clsP[1]), U2H(w0.y), a);
            a = DOT2(U2H(S[oo].clsP[2]), U2H(w0.z), a);
            a = DOT2(U2H(S[oo].clsP[3]), U2H(w0.w), a);
            a = DOT2(U2H(S[oo].clsP[4]), U2H(w1.x), a);
            a = DOT2(U2H(S[oo].clsP[5]), U2H(w1.y), a);
            a = DOT2(U2H(S[oo].clsP[6]), U2H(w1.z), a);
            a = DOT2(U2H(S[oo].clsP[7]), U2H(w1.w), a);
            out[((long)(n2 >> 9) * 256 + ut) * 512 + (n2 & 511)] = a;
        }
    }
}

extern "C" void kernel_launch(void* const* d_in, const int* in_sizes, int n_in,
                              void* d_out, int out_size, void* d_ws, size_t ws_size,
                              hipStream_t stream) {
    const float* cf       = (const float*)d_in[0];
    const float* fe       = (const float*)d_in[1];
    const float* fb       = (const float*)d_in[2];
    const float* cls_tok  = (const float*)d_in[3];
    const float* te       = (const float*)d_in[4];
    const int*   role_ids = (const int*)  d_in[5];
    const float* ln1_s    = (const float*)d_in[6];
    const float* ln1_b    = (const float*)d_in[7];
    const float* qkv_w    = (const float*)d_in[8];
    const float* qkv_b    = (const float*)d_in[9];
    const float* out_w    = (const float*)d_in[10];
    const float* out_b    = (const float*)d_in[11];
    const float* ln2_s    = (const float*)d_in[12];
    const float* ln2_b    = (const float*)d_in[13];
    const float* ff1_w    = (const float*)d_in[14];
    const float* ff1_b    = (const float*)d_in[15];
    const float* ff2_w    = (const float*)d_in[16];
    const float* ff2_b    = (const float*)d_in[17];
    const float* c2h_w    = (const float*)d_in[18];
    const float* c2h_b    = (const float*)d_in[19];
    float* out = (float*)d_out;
    unsigned* ws = (unsigned*)d_ws;

    pack_kernel<<<16, 256, 0, stream>>>(qkv_w, qkv_b, out_w, out_b, ff1_w, ff1_b,
                                        ff2_w, ff2_b, c2h_w, c2h_b, fb, te,
                                        role_ids, ln1_s, ln1_b, ln2_s, ln2_b, ws);
    enc_kernel<<<NBLK, 256, 0, stream>>>(cf, fe, cls_tok, ws, out);
}